// Round 25
// baseline (221.816 us; speedup 1.0000x reference)
//
#include <hip/hip_runtime.h>
#include <hip/hip_bf16.h>

// Fused causal SDPA, fp32 I/O, bf16 MFMA compute, materializes softmax weights.
// B=2 H=16 S=2048 DK=DV=128. d_out = [O: B*H*S*DV | W: B*H*S*S] fp32.
//
// R24 = exact R20 (212.3 us) + ONE change: Q is converted to pre-scaled bf16
//   in the convert kernel (conv_kvq: blocks [0,2048) K, [2048,3072) V,
//   [3072,4096) Q). attn_main reads bf16 Q fragments with one short8 load
//   per ds (16B) instead of 2 f32x4 loads + 8 cvts: -17MB HBM reads and the
//   whole prologue convert VALU removed. Loop bodies byte-identical to R20.

typedef __attribute__((ext_vector_type(4))) float  f32x4;
typedef __attribute__((ext_vector_type(8))) short  short8;
typedef __attribute__((ext_vector_type(4))) short  short4v;

#define S_LEN 2048
#define DKK   128
#define QBLK  128
#define KBLK  64
#define NBH   32
#define NW    8

__device__ __forceinline__ short f2bf(float f) {
    return __builtin_bit_cast(short, __float2bfloat16(f));
}

__device__ __forceinline__ void g2l16(const void* g, void* l) {
    __builtin_amdgcn_global_load_lds(
        (const __attribute__((address_space(1))) unsigned int*)g,
        (__attribute__((address_space(3))) unsigned int*)l, 16, 0, 0);
}

// ---------------- fused convert kernel ----------------
// blocks [0, 2048): K fp32 -> bf16, row-swizzled (chunk c -> c^(row&7))
// blocks [2048, 3072): V fp32 -> bf16 transposed VT[d][k], swizzled
// blocks [3072, 4096): Q fp32 -> bf16 * QSCALE, linear layout

__global__ __launch_bounds__(256) void conv_kvq(const float* __restrict__ K,
                                                const float* __restrict__ V,
                                                const float* __restrict__ Q,
                                                short* __restrict__ Kb,
                                                short* __restrict__ VT,
                                                short* __restrict__ Qs) {
    if (blockIdx.x < 2048) {
        const int NCH = NBH * S_LEN * (DKK / 8);
        for (int g = blockIdx.x * 256 + threadIdx.x; g < NCH; g += 2048 * 256) {
            const int row = g >> 4;          // global k row (bh*2048 + k)
            const int c   = g & 15;          // 16B chunk within 256B row
            const float* p = K + (size_t)row * DKK + c * 8;
            f32x4 a = *(const f32x4*)p;
            f32x4 b = *(const f32x4*)(p + 4);
            short8 r;
            #pragma unroll
            for (int j = 0; j < 4; ++j) {
                r[j]     = f2bf(a[j]);
                r[4 + j] = f2bf(b[j]);
            }
            *(short8*)(Kb + (size_t)row * DKK + (size_t)(c ^ (row & 7)) * 8) = r;
        }
    } else if (blockIdx.x < 3072) {
        __shared__ short tile[64][130];      // [k][d], padded
        const int ib = blockIdx.x - 2048;
        const int bh = ib >> 5;
        const int kt = ib & 31;              // 64-k tile
        const float* Vb = V + ((size_t)bh * S_LEN + kt * 64) * DKK;
        const int t  = threadIdx.x;
        const int k8 = t >> 5, d0 = (t & 31) * 4;
        #pragma unroll
        for (int it = 0; it < 8; ++it) {
            int k = it * 8 + k8;
            f32x4 v = *(const f32x4*)(Vb + (size_t)k * DKK + d0);
            #pragma unroll
            for (int j = 0; j < 4; ++j) tile[k][d0 + j] = f2bf(v[j]);
        }
        __syncthreads();
        const int d = t >> 1, half = t & 1;
        short* outb = VT + (size_t)bh * DKK * S_LEN + (size_t)d * S_LEN + kt * 64;
        #pragma unroll
        for (int cc = 0; cc < 4; ++cc) {
            short8 r;
            #pragma unroll
            for (int j = 0; j < 8; ++j) r[j] = tile[half * 32 + cc * 8 + j][d];
            int cp = (half * 4 + cc) ^ (d & 7);   // baked swizzle, 128B segment
            *(short8*)(outb + cp * 8) = r;
        }
    } else {
        const float QSCALE = 0.08838834764831845f * 1.4426950408889634f;
        const int NCH = NBH * S_LEN * (DKK / 8);
        for (int g = (blockIdx.x - 3072) * 256 + threadIdx.x; g < NCH;
             g += 1024 * 256) {
            const float* p = Q + (size_t)g * 8;
            f32x4 a = *(const f32x4*)p;
            f32x4 b = *(const f32x4*)(p + 4);
            short8 r;
            #pragma unroll
            for (int j = 0; j < 4; ++j) {
                r[j]     = f2bf(a[j] * QSCALE);
                r[4 + j] = f2bf(b[j] * QSCALE);
            }
            *(short8*)(Qs + (size_t)g * 8) = r;
        }
    }
}

// ---------------- main attention kernel ----------------

__global__ __launch_bounds__(512) void attn_main(
    const short* __restrict__ Qs, const short* __restrict__ Kb,
    const short* __restrict__ VT, float* __restrict__ O,
    float* __restrict__ W)
{
    __shared__ __align__(16) short kT[2][KBLK * DKK];    // 2 x 16KB
    __shared__ __align__(16) short vtT[2][DKK * KBLK];   // 2 x 16KB
    __shared__ __align__(16) short pT[NW][16 * KBLK];    // 16KB

    const int tid  = threadIdx.x;
    const int lane = tid & 63;
    const int w    = tid >> 6;           // 0..7
    const int lg   = lane >> 4;
    const int lr   = lane & 15;
    const int s7   = lr & 7;

    // XCD-grouped bh, heavy q-tiles first (grid 512: 16 qt per bh)
    const int i  = blockIdx.x;
    const int bh = (i & 7) * 4 + ((i >> 3) & 3);
    const int qt = 15 - (i >> 5);
    const int q0 = qt * QBLK;
    const int qbase = q0 + w * 16;
    const int kend  = q0 + QBLK;
    const int ntk   = kend / KBLK;       // 2*qt + 2   (64-wide tiles, pass 2)
    const int ntk1  = qt + 1;            // 128-wide tiles, pass 1
    const int qg    = qbase + lr;        // this lane's q row (both passes)

    const short* Kbh = Kb + (size_t)bh * S_LEN * DKK;
    const short* VTb = VT + (size_t)bh * DKK * S_LEN;
    float* Ob = O + (size_t)bh * S_LEN * DKK;
    float* Wb = W + (size_t)bh * S_LEN * S_LEN;

    // pass-1 staging: 128 K rows -> kT[buf] (rows 0..63) + vtT[buf] (64..127)
    auto stage_k2 = [&](int buf, int kt2) {
        const char* gk = (const char*)(Kbh + (size_t)kt2 * 128 * DKK); // 32KB
        char* lk = (char*)kT[buf];
        char* lv = (char*)vtT[buf];
        #pragma unroll
        for (int ii = 0; ii < 2; ++ii) {
            g2l16(gk + ii * 8192 + tid * 16,         lk + ii * 8192 + w * 1024);
            g2l16(gk + 16384 + ii * 8192 + tid * 16, lv + ii * 8192 + w * 1024);
        }
    };
    // pass-2 staging
    auto stage_k = [&](int buf, int kt_) {
        const char* gk = (const char*)(Kbh + (size_t)kt_ * KBLK * DKK); // 16KB
        char* lk = (char*)kT[buf];
        #pragma unroll
        for (int ii = 0; ii < 2; ++ii)
            g2l16(gk + ii * 8192 + tid * 16, lk + ii * 8192 + w * 1024);
    };
    auto stage_v = [&](int buf, int kt_) {
        const char* gv = (const char*)VTb + (size_t)kt_ * (KBLK * 2);   // 128B segs
        char* lv = (char*)vtT[buf];
        #pragma unroll
        for (int ii = 0; ii < 2; ++ii) {
            const int L = ii * 8192 + tid * 16;          // linear LDS byte
            g2l16(gv + (size_t)(L >> 7) * (S_LEN * 2) + (L & 127),
                  lv + ii * 8192 + w * 1024);
        }
    };

    // prologue: prestage pass-1 tiles 0 and 1 (concurrent fetch)
    stage_k2(0, 0);
    if (ntk1 > 1) stage_k2(1, 1);

    // Q fragments: pre-scaled bf16, one 16B load per ds
    short8 qf[4];
    {
        const short* qp = Qs + ((size_t)bh * S_LEN + qg) * DKK + lg * 8;
        #pragma unroll
        for (int ds = 0; ds < 4; ++ds)
            qf[ds] = *(const short8*)(qp + ds * 32);
    }

    // K fragment: k-row (within 64-row buffer) = 16t'+lr, d = lg*16+ds*64
    auto k_frag = [&](const char* kBc, int t, int ds) -> short8 {
        const int off = ((16 * t + lr) * 256 + ds * 64 + lg * 16) ^ (s7 << 4);
        return *(const short8*)(kBc + off);
    };

    // ================= PASS 1: row sums, 128-wide K tiles =================
    float lsum = 0.f;
    int cur = 0;
    for (int kt_ = 0; kt_ < ntk1; ++kt_) {
        __syncthreads();
        if (kt_ >= 1 && kt_ + 1 < ntk1) stage_k2(cur ^ 1, kt_ + 1);
        const int k0 = kt_ * 128;
        const char* kLo = (const char*)kT[cur];
        const char* kHi = (const char*)vtT[cur];
        #pragma unroll
        for (int t = 0; t < 8; ++t) {
            const char* kBc = (t < 4) ? kLo : kHi;
            const int   tt  = t & 3;
            f32x4 d = {0.f, 0.f, 0.f, 0.f};
            __builtin_amdgcn_s_setprio(1);
            #pragma unroll
            for (int ds = 0; ds < 4; ++ds)
                d = __builtin_amdgcn_mfma_f32_16x16x32_bf16(
                        k_frag(kBc, tt, ds), qf[ds], d, 0, 0, 0);
            __builtin_amdgcn_s_setprio(0);
            const int kb = k0 + 16 * t + lg * 4;
            #pragma unroll
            for (int r = 0; r < 4; ++r)
                lsum += (kb + r <= qg) ? exp2f(d[r]) : 0.f;
        }
        cur ^= 1;
    }
    lsum += __shfl_xor(lsum, 16);    // sum the 4 lg groups holding row qg
    lsum += __shfl_xor(lsum, 32);
    const float invl = 1.0f / lsum;

    // ================= PASS 2: normalized W + PV =================
    f32x4 acc[8];
    #pragma unroll
    for (int ii = 0; ii < 8; ++ii) acc[ii] = (f32x4){0.f, 0.f, 0.f, 0.f};

    __syncthreads();             // pass-1 LDS reads done before restaging
    cur = 0;
    stage_k(0, 0);
    stage_v(0, 0);
    for (int kt_ = 0; kt_ < ntk; ++kt_) {
        __syncthreads();
        if (kt_ + 1 < ntk) { stage_k(cur ^ 1, kt_ + 1); stage_v(cur ^ 1, kt_ + 1); }
        const int k0 = kt_ * KBLK;
        const char* kBc = (const char*)kT[cur];
        const char* vBc = (const char*)vtT[cur];
        char* pBc = (char*)pT[w];
        const bool live = (k0 <= qbase + 15);   // wave-uniform

        if (live) {
            #pragma unroll
            for (int t = 0; t < 4; ++t) {
                f32x4 d = {0.f, 0.f, 0.f, 0.f};
                __builtin_amdgcn_s_setprio(1);
                #pragma unroll
                for (int ds = 0; ds < 4; ++ds)
                    d = __builtin_amdgcn_mfma_f32_16x16x32_bf16(
                            k_frag(kBc, t, ds), qf[ds], d, 0, 0, 0);
                __builtin_amdgcn_s_setprio(0);
                const int kb = k0 + 16 * t + lg * 4;
                f32x4 pv;
                short4v pb;
                #pragma unroll
                for (int r = 0; r < 4; ++r) {
                    const float p = (kb + r <= qg) ? exp2f(d[r]) * invl : 0.f;
                    pv[r] = p;
                    pb[r] = f2bf(p);
                }
                *(f32x4*)(Wb + (size_t)qg * S_LEN + kb) = pv;
                const int poff = lr * 128 + (((16 * t + lg * 4) * 2) ^ (s7 << 4));
                *(short4v*)(pBc + poff) = pb;
            }
            #pragma unroll
            for (int h = 0; h < 2; ++h) {
                const int poff = lr * 128 + ((h * 64 + lg * 16) ^ (s7 << 4));
                short8 pa = *(const short8*)(pBc + poff);
                __builtin_amdgcn_s_setprio(1);
                #pragma unroll
                for (int nt = 0; nt < 8; ++nt) {
                    const int voff = (nt * 16 + lr) * 128 + ((h * 64 + lg * 16) ^ (s7 << 4));
                    short8 vf = *(const short8*)(vBc + voff);
                    acc[nt] = __builtin_amdgcn_mfma_f32_16x16x32_bf16(pa, vf, acc[nt], 0, 0, 0);
                }
                __builtin_amdgcn_s_setprio(0);
            }
        } else {
            // fully-masked for this wave: W zeros still required
            const f32x4 z = {0.f, 0.f, 0.f, 0.f};
            #pragma unroll
            for (int t = 0; t < 4; ++t)
                *(f32x4*)(Wb + (size_t)qg * S_LEN + k0 + 16 * t + lg * 4) = z;
        }
        cur ^= 1;
    }

    // ---- O store: lane q = qbase+lg*4+r, dv = nt*16+lr
    #pragma unroll
    for (int nt = 0; nt < 8; ++nt)
        #pragma unroll
        for (int r = 0; r < 4; ++r)
            Ob[(size_t)(qbase + lg * 4 + r) * DKK + nt * 16 + lr] = acc[nt][r];

    // ---- zero-fill W cols [kend, S) for rows [q0, q0+128)
    const int zc = S_LEN - kend;
    if (zc > 0) {
        const int yo = tid >> 2;     // row 0..127
        const int xo = tid & 3;
        float* wrow = Wb + (size_t)(q0 + yo) * S_LEN + kend;
        const f32x4 z = {0.f, 0.f, 0.f, 0.f};
        for (int c = xo * 4; c < zc; c += 16)
            *(f32x4*)(wrow + c) = z;
    }
}

extern "C" void kernel_launch(void* const* d_in, const int* in_sizes, int n_in,
                              void* d_out, int out_size, void* d_ws, size_t ws_size,
                              hipStream_t stream) {
    const float* Q = (const float*)d_in[0];
    const float* K = (const float*)d_in[1];
    const float* V = (const float*)d_in[2];
    float* O = (float*)d_out;
    float* W = (float*)d_out + (size_t)NBH * S_LEN * DKK;

    const size_t TEN = (size_t)NBH * S_LEN * DKK;   // 8,388,608 elements
    short* Kb  = (short*)d_ws;
    short* VTw = Kb + TEN;
    short* Qs  = VTw + TEN;

    conv_kvq<<<4096, 256, 0, stream>>>(K, V, Q, Kb, VTw, Qs);
    attn_main<<<NBH * (S_LEN / QBLK), 512, 0, stream>>>(Qs, Kb, VTw, O, W);
}

// Round 26
// 210.379 us; speedup vs baseline: 1.0544x; 1.0544x over previous
//
#include <hip/hip_runtime.h>
#include <hip/hip_bf16.h>

// Fused causal SDPA, fp32 I/O, bf16 MFMA compute, materializes softmax weights.
// B=2 H=16 S=2048 DK=DV=128. d_out = [O: B*H*S*DV | W: B*H*S*S] fp32.
//
// R25 = exact R20 (212.3 us), the session's best kernel, resubmitted to lock
//   in as final. Structure: fused conv_kv (bf16 K row-swizzled + V^T
//   swizzled); attn_main 512 threads (8 waves x 16 q rows, QBLK=128,
//   80KB LDS -> 2 blocks/CU); pass 1 = row sums over 128-wide K tiles
//   (kT+vtT as 2x32KB dbuf, tiles 0/1 prestaged, swapped mfma(K,Q));
//   pass 2 = normalized W (f32x4 stores) + P->LDS (short4) -> PV;
//   epilogue O store + upper-triangle zero-fill.

typedef __attribute__((ext_vector_type(4))) float  f32x4;
typedef __attribute__((ext_vector_type(8))) short  short8;
typedef __attribute__((ext_vector_type(4))) short  short4v;

#define S_LEN 2048
#define DKK   128
#define QBLK  128
#define KBLK  64
#define NBH   32
#define NW    8

__device__ __forceinline__ short f2bf(float f) {
    return __builtin_bit_cast(short, __float2bfloat16(f));
}

__device__ __forceinline__ void g2l16(const void* g, void* l) {
    __builtin_amdgcn_global_load_lds(
        (const __attribute__((address_space(1))) unsigned int*)g,
        (__attribute__((address_space(3))) unsigned int*)l, 16, 0, 0);
}

// ---------------- fused convert kernel ----------------

__global__ __launch_bounds__(256) void conv_kv(const float* __restrict__ K,
                                               const float* __restrict__ V,
                                               short* __restrict__ Kb,
                                               short* __restrict__ VT) {
    if (blockIdx.x < 2048) {
        const int NCH = NBH * S_LEN * (DKK / 8);
        for (int g = blockIdx.x * 256 + threadIdx.x; g < NCH; g += 2048 * 256) {
            const int row = g >> 4;          // global k row (bh*2048 + k)
            const int c   = g & 15;          // 16B chunk within 256B row
            const float* p = K + (size_t)row * DKK + c * 8;
            f32x4 a = *(const f32x4*)p;
            f32x4 b = *(const f32x4*)(p + 4);
            short8 r;
            #pragma unroll
            for (int j = 0; j < 4; ++j) {
                r[j]     = f2bf(a[j]);
                r[4 + j] = f2bf(b[j]);
            }
            *(short8*)(Kb + (size_t)row * DKK + (size_t)(c ^ (row & 7)) * 8) = r;
        }
    } else {
        __shared__ short tile[64][130];      // [k][d], padded
        const int ib = blockIdx.x - 2048;
        const int bh = ib >> 5;
        const int kt = ib & 31;              // 64-k tile
        const float* Vb = V + ((size_t)bh * S_LEN + kt * 64) * DKK;
        const int t  = threadIdx.x;
        const int k8 = t >> 5, d0 = (t & 31) * 4;
        #pragma unroll
        for (int it = 0; it < 8; ++it) {
            int k = it * 8 + k8;
            f32x4 v = *(const f32x4*)(Vb + (size_t)k * DKK + d0);
            #pragma unroll
            for (int j = 0; j < 4; ++j) tile[k][d0 + j] = f2bf(v[j]);
        }
        __syncthreads();
        const int d = t >> 1, half = t & 1;
        short* outb = VT + (size_t)bh * DKK * S_LEN + (size_t)d * S_LEN + kt * 64;
        #pragma unroll
        for (int cc = 0; cc < 4; ++cc) {
            short8 r;
            #pragma unroll
            for (int j = 0; j < 8; ++j) r[j] = tile[half * 32 + cc * 8 + j][d];
            int cp = (half * 4 + cc) ^ (d & 7);   // baked swizzle, 128B segment
            *(short8*)(outb + cp * 8) = r;
        }
    }
}

// ---------------- main attention kernel ----------------

__global__ __launch_bounds__(512) void attn_main(
    const float* __restrict__ Qf, const short* __restrict__ Kb,
    const short* __restrict__ VT, float* __restrict__ O,
    float* __restrict__ W)
{
    __shared__ __align__(16) short kT[2][KBLK * DKK];    // 2 x 16KB
    __shared__ __align__(16) short vtT[2][DKK * KBLK];   // 2 x 16KB
    __shared__ __align__(16) short pT[NW][16 * KBLK];    // 16KB

    const int tid  = threadIdx.x;
    const int lane = tid & 63;
    const int w    = tid >> 6;           // 0..7
    const int lg   = lane >> 4;
    const int lr   = lane & 15;
    const int s7   = lr & 7;

    // XCD-grouped bh, heavy q-tiles first (grid 512: 16 qt per bh)
    const int i  = blockIdx.x;
    const int bh = (i & 7) * 4 + ((i >> 3) & 3);
    const int qt = 15 - (i >> 5);
    const int q0 = qt * QBLK;
    const int qbase = q0 + w * 16;
    const int kend  = q0 + QBLK;
    const int ntk   = kend / KBLK;       // 2*qt + 2   (64-wide tiles, pass 2)
    const int ntk1  = qt + 1;            // 128-wide tiles, pass 1
    const int qg    = qbase + lr;        // this lane's q row (both passes)

    const short* Kbh = Kb + (size_t)bh * S_LEN * DKK;
    const short* VTb = VT + (size_t)bh * DKK * S_LEN;
    float* Ob = O + (size_t)bh * S_LEN * DKK;
    float* Wb = W + (size_t)bh * S_LEN * S_LEN;

    // pass-1 staging: 128 K rows -> kT[buf] (rows 0..63) + vtT[buf] (64..127)
    auto stage_k2 = [&](int buf, int kt2) {
        const char* gk = (const char*)(Kbh + (size_t)kt2 * 128 * DKK); // 32KB
        char* lk = (char*)kT[buf];
        char* lv = (char*)vtT[buf];
        #pragma unroll
        for (int ii = 0; ii < 2; ++ii) {
            g2l16(gk + ii * 8192 + tid * 16,         lk + ii * 8192 + w * 1024);
            g2l16(gk + 16384 + ii * 8192 + tid * 16, lv + ii * 8192 + w * 1024);
        }
    };
    // pass-2 staging
    auto stage_k = [&](int buf, int kt_) {
        const char* gk = (const char*)(Kbh + (size_t)kt_ * KBLK * DKK); // 16KB
        char* lk = (char*)kT[buf];
        #pragma unroll
        for (int ii = 0; ii < 2; ++ii)
            g2l16(gk + ii * 8192 + tid * 16, lk + ii * 8192 + w * 1024);
    };
    auto stage_v = [&](int buf, int kt_) {
        const char* gv = (const char*)VTb + (size_t)kt_ * (KBLK * 2);   // 128B segs
        char* lv = (char*)vtT[buf];
        #pragma unroll
        for (int ii = 0; ii < 2; ++ii) {
            const int L = ii * 8192 + tid * 16;          // linear LDS byte
            g2l16(gv + (size_t)(L >> 7) * (S_LEN * 2) + (L & 127),
                  lv + ii * 8192 + w * 1024);
        }
    };

    // prologue: prestage pass-1 tiles 0 and 1 (concurrent fetch)
    stage_k2(0, 0);
    if (ntk1 > 1) stage_k2(1, 1);

    // Q fragments converted in-kernel: lane q = qg, d = lg*8+ds*32+j
    const float QSCALE = 0.08838834764831845f * 1.4426950408889634f;
    short8 qf[4];
    {
        const float* qp = Qf + ((size_t)bh * S_LEN + qg) * DKK + lg * 8;
        #pragma unroll
        for (int ds = 0; ds < 4; ++ds) {
            f32x4 a = *(const f32x4*)(qp + ds * 32);
            f32x4 b = *(const f32x4*)(qp + ds * 32 + 4);
            short8 r;
            #pragma unroll
            for (int jj = 0; jj < 4; ++jj) {
                r[jj]     = f2bf(a[jj] * QSCALE);
                r[4 + jj] = f2bf(b[jj] * QSCALE);
            }
            qf[ds] = r;
        }
    }

    // K fragment: k-row (within 64-row buffer) = 16t'+lr, d = lg*16+ds*64
    auto k_frag = [&](const char* kBc, int t, int ds) -> short8 {
        const int off = ((16 * t + lr) * 256 + ds * 64 + lg * 16) ^ (s7 << 4);
        return *(const short8*)(kBc + off);
    };

    // ================= PASS 1: row sums, 128-wide K tiles =================
    float lsum = 0.f;
    int cur = 0;
    for (int kt_ = 0; kt_ < ntk1; ++kt_) {
        __syncthreads();
        if (kt_ >= 1 && kt_ + 1 < ntk1) stage_k2(cur ^ 1, kt_ + 1);
        const int k0 = kt_ * 128;
        const char* kLo = (const char*)kT[cur];
        const char* kHi = (const char*)vtT[cur];
        #pragma unroll
        for (int t = 0; t < 8; ++t) {
            const char* kBc = (t < 4) ? kLo : kHi;
            const int   tt  = t & 3;
            f32x4 d = {0.f, 0.f, 0.f, 0.f};
            __builtin_amdgcn_s_setprio(1);
            #pragma unroll
            for (int ds = 0; ds < 4; ++ds)
                d = __builtin_amdgcn_mfma_f32_16x16x32_bf16(
                        k_frag(kBc, tt, ds), qf[ds], d, 0, 0, 0);
            __builtin_amdgcn_s_setprio(0);
            const int kb = k0 + 16 * t + lg * 4;
            #pragma unroll
            for (int r = 0; r < 4; ++r)
                lsum += (kb + r <= qg) ? exp2f(d[r]) : 0.f;
        }
        cur ^= 1;
    }
    lsum += __shfl_xor(lsum, 16);    // sum the 4 lg groups holding row qg
    lsum += __shfl_xor(lsum, 32);
    const float invl = 1.0f / lsum;

    // ================= PASS 2: normalized W + PV =================
    f32x4 acc[8];
    #pragma unroll
    for (int ii = 0; ii < 8; ++ii) acc[ii] = (f32x4){0.f, 0.f, 0.f, 0.f};

    __syncthreads();             // pass-1 LDS reads done before restaging
    cur = 0;
    stage_k(0, 0);
    stage_v(0, 0);
    for (int kt_ = 0; kt_ < ntk; ++kt_) {
        __syncthreads();
        if (kt_ + 1 < ntk) { stage_k(cur ^ 1, kt_ + 1); stage_v(cur ^ 1, kt_ + 1); }
        const int k0 = kt_ * KBLK;
        const char* kBc = (const char*)kT[cur];
        const char* vBc = (const char*)vtT[cur];
        char* pBc = (char*)pT[w];
        const bool live = (k0 <= qbase + 15);   // wave-uniform

        if (live) {
            #pragma unroll
            for (int t = 0; t < 4; ++t) {
                f32x4 d = {0.f, 0.f, 0.f, 0.f};
                __builtin_amdgcn_s_setprio(1);
                #pragma unroll
                for (int ds = 0; ds < 4; ++ds)
                    d = __builtin_amdgcn_mfma_f32_16x16x32_bf16(
                            k_frag(kBc, t, ds), qf[ds], d, 0, 0, 0);
                __builtin_amdgcn_s_setprio(0);
                const int kb = k0 + 16 * t + lg * 4;
                f32x4 pv;
                short4v pb;
                #pragma unroll
                for (int r = 0; r < 4; ++r) {
                    const float p = (kb + r <= qg) ? exp2f(d[r]) * invl : 0.f;
                    pv[r] = p;
                    pb[r] = f2bf(p);
                }
                *(f32x4*)(Wb + (size_t)qg * S_LEN + kb) = pv;
                const int poff = lr * 128 + (((16 * t + lg * 4) * 2) ^ (s7 << 4));
                *(short4v*)(pBc + poff) = pb;
            }
            #pragma unroll
            for (int h = 0; h < 2; ++h) {
                const int poff = lr * 128 + ((h * 64 + lg * 16) ^ (s7 << 4));
                short8 pa = *(const short8*)(pBc + poff);
                __builtin_amdgcn_s_setprio(1);
                #pragma unroll
                for (int nt = 0; nt < 8; ++nt) {
                    const int voff = (nt * 16 + lr) * 128 + ((h * 64 + lg * 16) ^ (s7 << 4));
                    short8 vf = *(const short8*)(vBc + voff);
                    acc[nt] = __builtin_amdgcn_mfma_f32_16x16x32_bf16(pa, vf, acc[nt], 0, 0, 0);
                }
                __builtin_amdgcn_s_setprio(0);
            }
        } else {
            // fully-masked for this wave: W zeros still required
            const f32x4 z = {0.f, 0.f, 0.f, 0.f};
            #pragma unroll
            for (int t = 0; t < 4; ++t)
                *(f32x4*)(Wb + (size_t)qg * S_LEN + k0 + 16 * t + lg * 4) = z;
        }
        cur ^= 1;
    }

    // ---- O store: lane q = qbase+lg*4+r, dv = nt*16+lr
    #pragma unroll
    for (int nt = 0; nt < 8; ++nt)
        #pragma unroll
        for (int r = 0; r < 4; ++r)
            Ob[(size_t)(qbase + lg * 4 + r) * DKK + nt * 16 + lr] = acc[nt][r];

    // ---- zero-fill W cols [kend, S) for rows [q0, q0+128)
    const int zc = S_LEN - kend;
    if (zc > 0) {
        const int yo = tid >> 2;     // row 0..127
        const int xo = tid & 3;
        float* wrow = Wb + (size_t)(q0 + yo) * S_LEN + kend;
        const f32x4 z = {0.f, 0.f, 0.f, 0.f};
        for (int c = xo * 4; c < zc; c += 16)
            *(f32x4*)(wrow + c) = z;
    }
}

extern "C" void kernel_launch(void* const* d_in, const int* in_sizes, int n_in,
                              void* d_out, int out_size, void* d_ws, size_t ws_size,
                              hipStream_t stream) {
    const float* Q = (const float*)d_in[0];
    const float* K = (const float*)d_in[1];
    const float* V = (const float*)d_in[2];
    float* O = (float*)d_out;
    float* W = (float*)d_out + (size_t)NBH * S_LEN * DKK;

    const size_t TEN = (size_t)NBH * S_LEN * DKK;   // 8,388,608 elements
    short* Kb  = (short*)d_ws;
    short* VTw = Kb + TEN;

    conv_kv<<<3072, 256, 0, stream>>>(K, V, Kb, VTw);
    attn_main<<<NBH * (S_LEN / QBLK), 512, 0, stream>>>(Q, Kb, VTw, O, W);
}